// Round 9
// baseline (615.023 us; speedup 1.0000x reference)
//
#include <hip/hip_runtime.h>
#include <stdint.h>

#define C_HID 128
#define NGRAPH 64
#define COUT 64
#define POOL_S 64     // pool chunks per graph
#define NBLK 256      // edge-chunk blocks for cnt/scat
#define BKT 256       // nodes per bucket
#define NBUK_MAX 512

typedef short bf16x8 __attribute__((ext_vector_type(8)));
typedef float f32x4 __attribute__((ext_vector_type(4)));

__device__ __forceinline__ unsigned short f2bf(float f){
  unsigned int u = __builtin_bit_cast(unsigned int, f);
  u = u + 0x7FFFu + ((u >> 16) & 1u);   // RNE
  return (unsigned short)(u >> 16);
}
__device__ __forceinline__ float bflo(unsigned int u){
  return __builtin_bit_cast(float, u << 16);
}
__device__ __forceinline__ float bfhi(unsigned int u){
  return __builtin_bit_cast(float, u & 0xFFFF0000u);
}
__device__ __forceinline__ int clampi(int v, int lo, int hi){
  return v < lo ? lo : (v > hi ? hi : v);
}

__global__ void k_zero(float* __restrict__ out, int n){
  int i = blockIdx.x*blockDim.x + threadIdx.x;
  if (i < n) out[i] = 0.f;
}

// ---------- CSR build, pass 1: per-(block,bucket) histogram ----------
__global__ __launch_bounds__(256) void k_cnt(const int* __restrict__ dst,
                                             int* __restrict__ cntg,
                                             int E, int N, int NBUK, int chunk){
  __shared__ int cnt[NBUK_MAX];
  int blk = blockIdx.x, t = threadIdx.x;
  for (int b = t; b < NBUK; b += 256) cnt[b] = 0;
  __syncthreads();
  int e0 = blk*chunk, e1 = min(E, e0 + chunk);
  for (int e = e0 + t; e < e1; e += 256)
    atomicAdd(&cnt[clampi(dst[e], 0, N-1) >> 8], 1);
  __syncthreads();
  for (int b = t; b < NBUK; b += 256)
    cntg[b*NBLK + blk] = cnt[b];          // bucket-major layout for the scan
}

// ---------- pass 2: exclusive scan of n = NBUK*NBLK counts (single block) ----------
__global__ __launch_bounds__(1024) void k_scan(const int* __restrict__ cnt,
                                               int* __restrict__ bases, int n){
  __shared__ int chs[1024];
  int t = threadIdx.x;
  int per = (n + 1023) / 1024;
  int base = t * per;
  int s = 0;
  for (int j = 0; j < per; ++j){
    int i = base + j;
    s += (i < n) ? cnt[i] : 0;
  }
  chs[t] = s;
  __syncthreads();
  for (int off = 1; off < 1024; off <<= 1){
    int add = (t >= off) ? chs[t-off] : 0;
    __syncthreads();
    chs[t] += add;
    __syncthreads();
  }
  int run = chs[t] - s;                    // exclusive chunk base
  for (int j = 0; j < per; ++j){
    int i = base + j;
    if (i < n){ bases[i] = run; run += cnt[i]; }
  }
  if (t == 1023) bases[n] = chs[1023];
}

// ---------- pass 3: scatter packed records into per-(block,bucket) segments ----------
// Each block writes only its own contiguous segments -> one XCD per line, no global atomics.
__global__ __launch_bounds__(256) void k_scat(const int* __restrict__ src,
                                              const int* __restrict__ dst,
                                              const int* __restrict__ bases,
                                              unsigned int* __restrict__ rec,
                                              int E, int N, int NBUK, int chunk){
  __shared__ int cur[NBUK_MAX];
  int blk = blockIdx.x, t = threadIdx.x;
  for (int b = t; b < NBUK; b += 256) cur[b] = bases[b*NBLK + blk];
  __syncthreads();
  int e0 = blk*chunk, e1 = min(E, e0 + chunk);
  for (int e = e0 + t; e < e1; e += 256){
    int d = clampi(dst[e], 0, N-1);
    int s = clampi(src[e], 0, N-1);
    int p = atomicAdd(&cur[d >> 8], 1);    // LDS atomic
    rec[p] = (unsigned int)s | ((unsigned int)(d & 255) << 24);
  }
}

// ---------- pass 4: per-bucket local CSR (offs, dinv, meta) ----------
__global__ __launch_bounds__(256) void k_csr(const unsigned int* __restrict__ rec,
                                             const int* __restrict__ bases,
                                             int* __restrict__ offs, float* __restrict__ dinv,
                                             int* __restrict__ meta, int E, int N, int NBUK){
  __shared__ int cnt[BKT], loff[BKT], cur[BKT];
  int b = blockIdx.x, t = threadIdx.x;
  cnt[t] = 0;
  __syncthreads();
  int r0 = bases[b*NBLK];
  int r1 = (b+1 < NBUK) ? bases[(b+1)*NBLK] : E;
  for (int i = r0 + t; i < r1; i += 256)
    atomicAdd(&cnt[rec[i] >> 24], 1);
  __syncthreads();
  loff[t] = cnt[t];
  __syncthreads();
  for (int off = 1; off < BKT; off <<= 1){
    int add = (t >= off) ? loff[t - off] : 0;
    __syncthreads();
    loff[t] += add;
    __syncthreads();
  }
  int excl = loff[t] - cnt[t];
  cur[t] = r0 + excl;
  int node = b*BKT + t;
  if (node < N){
    offs[node] = r0 + excl;
    dinv[node] = rsqrtf((float)(cnt[t] + 1));   // +1 = self loop
  }
  if (b == NBUK-1 && t == 0) offs[N] = E;
  __syncthreads();
  for (int i = r0 + t; i < r1; i += 256){
    unsigned int r = rec[i];
    int p = atomicAdd(&cur[r >> 24], 1);
    meta[p] = (int)(r & 0x00FFFFFFu);
  }
}

// ---------- y0 = dinv * x0, fp32 -> packed bf16; also zero row N (gather sink) ----------
__global__ void k_xcast(const float2* __restrict__ x, const float* __restrict__ dinv,
                        unsigned int* __restrict__ o, int N){
  int i = blockIdx.x*256 + threadIdx.x;
  int tot = N*64;
  if (i < tot){
    float2 v = x[i];
    float dn = dinv[i >> 6];
    o[i] = (unsigned int)f2bf(v.x*dn) | ((unsigned int)f2bf(v.y*dn) << 16);
  } else if (i < tot + 64){
    o[i] = 0;                       // zero row at index N
  }
}

// ---------- W fp32 [128][128] -> Wt bf16 [n][k] (3 weights) ----------
__global__ void k_prep(const float* __restrict__ W1, const float* __restrict__ W2,
                       const float* __restrict__ W3, unsigned short* __restrict__ Wt){
  int idx = blockIdx.x*256 + threadIdx.x;     // grid = 192 blocks
  int w = idx >> 14;                           // 16384 per weight
  int r = idx & 16383;
  int n = r & 127, k = r >> 7;
  const float* W = (w == 0) ? W1 : (w == 1) ? W2 : W3;
  Wt[(size_t)w*16384 + (size_t)n*128 + k] = f2bf(W[k*128 + n]);
}

// ---------- SpMM: agg[i] = dinv[i] * ( y[i] + sum_e y[src_e] ) ----------
// y pre-scaled by dinv. One wave per node (uniform): meta reads are s_loads,
// gathers are SGPR-base + lane-offset. Tail gathers hit zero row N.
__global__ void k_spmm(const unsigned int* __restrict__ y, const int* __restrict__ offs,
                       const float* __restrict__ dinv, const int* __restrict__ meta,
                       unsigned int* __restrict__ agg, int N){
  int wv   = __builtin_amdgcn_readfirstlane(threadIdx.x >> 6);
  int lane = threadIdx.x & 63;
  int node = blockIdx.x*4 + wv;
  if (node >= N) return;
  int e0 = offs[node], e1 = offs[node+1];
  int cnt = e1 - e0;
  const int* mrow = meta + e0;

  float ax, ay;
  { unsigned int u = y[(size_t)node*64 + lane];   // self loop (y already dinv-scaled)
    ax = bflo(u); ay = bfhi(u); }

  for (int e = 0; e < cnt; e += 8){
    int s[8]; unsigned int u[8];
    #pragma unroll
    for (int j = 0; j < 8; ++j){
      int ij = e + j;
      int sj = mrow[ij];                           // uniform -> s_load (junk ok past cnt)
      s[j] = (ij < cnt) ? sj : N;                  // tail -> zero row
    }
    #pragma unroll
    for (int j = 0; j < 8; ++j)
      u[j] = y[(size_t)s[j]*64 + lane];            // SGPR base + lane offset
    #pragma unroll
    for (int j = 0; j < 8; ++j){
      ax += bflo(u[j]);
      ay += bfhi(u[j]);
    }
  }
  float dn = dinv[node];
  ax *= dn; ay *= dn;
  agg[(size_t)node*64 + lane] = (unsigned int)f2bf(ax) | ((unsigned int)f2bf(ay) << 16);
}

// ---------- GEMM: out = relu(A[Mx128] @ W + b) [* dinv[row] if SC] ----------
#define GEMM_BLOCKS 512
template<bool SC>
__global__ __launch_bounds__(256) void k_gemm(const unsigned short* __restrict__ A,
                                              const unsigned short* __restrict__ Wt,
                                              const float* __restrict__ bias,
                                              const float* __restrict__ scale,
                                              unsigned short* __restrict__ out, int M){
  __shared__ unsigned short wt[128*136];
  {
    const uint4* wsrc = (const uint4*)Wt;     // 4096 uint4 (8 shorts each)
    for (int i = threadIdx.x; i < 4096; i += 256){
      uint4 v = wsrc[i];
      int n = i >> 4, kblk = i & 15;          // row = 16 uint4
      *(uint4*)&wt[n*136 + kblk*8] = v;
    }
  }
  __syncthreads();

  int wv = threadIdx.x >> 6, lane = threadIdx.x & 63;
  int q = lane >> 4, ln = lane & 15;
  int tiles = (M + 63) >> 6;

  for (int tile = blockIdx.x; tile < tiles; tile += GEMM_BLOCKS){
    int m0 = tile*64 + wv*16;
    int arow = m0 + ln;
    bool arow_ok = (arow < M);
    int arow_s = arow_ok ? arow : 0;

    f32x4 zero = {0.f, 0.f, 0.f, 0.f};
    f32x4 acc[8];
    #pragma unroll
    for (int t = 0; t < 8; ++t) acc[t] = zero;

    #pragma unroll
    for (int kk = 0; kk < 4; ++kk){
      bf16x8 a;
      if (arow_ok){
        __builtin_memcpy(&a, A + (size_t)arow_s*128 + kk*32 + q*8, 16);
      } else {
        a = (bf16x8){0,0,0,0,0,0,0,0};
      }
      #pragma unroll
      for (int t = 0; t < 8; ++t){
        bf16x8 b;
        __builtin_memcpy(&b, &wt[(t*16 + ln)*136 + kk*32 + q*8], 16);
        acc[t] = __builtin_amdgcn_mfma_f32_16x16x32_bf16(a, b, acc[t], 0, 0, 0);
      }
    }
    float sc[4];
    #pragma unroll
    for (int r = 0; r < 4; ++r){
      int row = m0 + q*4 + r;
      sc[r] = (SC && row < M) ? scale[row] : 1.0f;
    }
    #pragma unroll
    for (int t = 0; t < 8; ++t){
      float bv = bias[t*16 + ln];
      #pragma unroll
      for (int r = 0; r < 4; ++r){
        int row = m0 + q*4 + r;
        if (row < M){
          float v = acc[t][r] + bv;
          v = v > 0.f ? v : 0.f;
          if (SC) v *= sc[r];
          out[(size_t)row*128 + t*16 + ln] = f2bf(v);
        }
      }
    }
  }
}

// ---------- pooling ----------
__device__ __forceinline__ int lower_bound_i(const int* arr, int n, int val){
  int lo = 0, hi = n;
  while (lo < hi){ int mid = (lo + hi) >> 1; if (arr[mid] < val) lo = mid + 1; else hi = mid; }
  return lo;
}

__global__ void k_pool(const unsigned int* __restrict__ x, const int* __restrict__ batch,
                       float* __restrict__ partial, int N){
  int g = blockIdx.x / POOL_S, s = blockIdx.x % POOL_S;
  int h = threadIdx.x >> 6;
  int lane = threadIdx.x & 63;
  int rs = clampi(lower_bound_i(batch, N, g), 0, N);
  int re = clampi(lower_bound_i(batch, N, g + 1), rs, N);
  int len = re - rs;
  int a = rs + (int)(((long long)len * s) / POOL_S);
  int b = rs + (int)(((long long)len * (s + 1)) / POOL_S);
  float ax = 0.f, ay = 0.f;
  for (int i = a + h; i < b; i += 2){
    unsigned int u = x[(size_t)i*64 + lane];
    ax += bflo(u);
    ay += bfhi(u);
  }
  float* p = partial + ((size_t)(g*POOL_S + s)*2 + h)*C_HID;
  p[2*lane]   = ax;
  p[2*lane+1] = ay;
}

__global__ void k_final(const float* __restrict__ partial, const int* __restrict__ batch,
                        const float* __restrict__ Wl, const float* __restrict__ bl,
                        float* __restrict__ out, int N){
  __shared__ float sums[C_HID];
  int g = blockIdx.x;
  int t = threadIdx.x;
  float acc = 0.f;
  const float* p = partial + (size_t)g*POOL_S*2*C_HID;
  for (int j = 0; j < POOL_S*2; ++j)
    acc += p[j*C_HID + t];
  sums[t] = acc;
  __syncthreads();
  if (t < COUT){
    int rs = clampi(lower_bound_i(batch, N, g), 0, N);
    int re = clampi(lower_bound_i(batch, N, g + 1), rs, N);
    float inv = 1.0f / fmaxf((float)(re - rs), 1.0f);
    float o = 0.f;
    for (int k = 0; k < 128; ++k)
      o += sums[k] * Wl[k*COUT + t];
    out[g*COUT + t] = o * inv + bl[t];
  }
}

extern "C" void kernel_launch(void* const* d_in, const int* in_sizes, int n_in,
                              void* d_out, int out_size, void* d_ws, size_t ws_size,
                              hipStream_t stream){
  const float* x0 = (const float*)d_in[0];
  const int* ei   = (const int*)d_in[1];
  const int* batch= (const int*)d_in[2];
  const float* W1 = (const float*)d_in[3];
  const float* b1 = (const float*)d_in[4];
  const float* W2 = (const float*)d_in[5];
  const float* b2 = (const float*)d_in[6];
  const float* W3 = (const float*)d_in[7];
  const float* b3 = (const float*)d_in[8];
  const float* Wl = (const float*)d_in[9];
  const float* bl = (const float*)d_in[10];
  float* out = (float*)d_out;

  int E = in_sizes[1] / 2;
  int N = in_sizes[2];
  const int* src = ei;
  const int* dst = ei + E;
  int NBUK = (N + BKT - 1) / BKT;
  int chunk = (E + NBLK - 1) / NBLK;
  int ncnt = NBUK * NBLK;

  size_t off_acc = 0;
  auto carve = [&](size_t bytes)->size_t{
    size_t r = off_acc; off_acc += (bytes + 255) & ~(size_t)255; return r;
  };
  size_t part_bytes = (size_t)NGRAPH*POOL_S*2*C_HID*4;      // 4 MB
  size_t rec_bytes  = (size_t)E*4;                          // 6.4 MB
  size_t o_cnt   = carve((size_t)ncnt*4);                   // per-(bucket,block) counts
  size_t o_bases = carve((size_t)(ncnt+1)*4);
  size_t o_offs  = carve((size_t)(N+1)*4);
  size_t o_dinv  = carve((size_t)N*4);
  size_t o_meta  = carve((size_t)E*4);                      // compact CSR src list
  size_t o_u     = carve(rec_bytes > part_bytes ? rec_bytes : part_bytes); // rec/part union
  size_t o_aggb  = carve((size_t)N*C_HID*2);                // bf16 ping
  size_t o_xbuf  = carve((size_t)(N+1)*C_HID*2);            // bf16 pong (+ zero row N)
  size_t o_wt    = carve((size_t)3*128*128*2);              // bf16 Wt x3
  size_t need = off_acc;

  if (ws_size < need || NBUK > NBUK_MAX){
    k_zero<<<(out_size+255)/256, 256, 0, stream>>>(out, out_size);
    return;
  }

  char* base = (char*)d_ws;
  int* cntg  = (int*)(base + o_cnt);
  int* bases = (int*)(base + o_bases);
  int* offs  = (int*)(base + o_offs);
  float* dinv= (float*)(base + o_dinv);
  int* meta  = (int*)(base + o_meta);
  unsigned int* rec  = (unsigned int*)(base + o_u);
  float* part        = (float*)(base + o_u);                // aliased (disjoint lifetime)
  unsigned int* aggb = (unsigned int*)(base + o_aggb);
  unsigned int* xbuf = (unsigned int*)(base + o_xbuf);
  unsigned short* wt = (unsigned short*)(base + o_wt);

  k_cnt <<<NBLK, 256, 0, stream>>>(dst, cntg, E, N, NBUK, chunk);
  k_scan<<<1, 1024, 0, stream>>>(cntg, bases, ncnt);
  k_scat<<<NBLK, 256, 0, stream>>>(src, dst, bases, rec, E, N, NBUK, chunk);
  k_csr <<<NBUK, BKT, 0, stream>>>(rec, bases, offs, dinv, meta, E, N, NBUK);

  k_xcast<<<(N*64 + 64 + 255)/256, 256, 0, stream>>>((const float2*)x0, dinv, xbuf, N);
  k_prep <<<192, 256, 0, stream>>>(W1, W2, W3, wt);

  int spmm_grid = (N + 3) / 4;     // 4 waves/block, one wave per node

  k_spmm<<<spmm_grid, 256, 0, stream>>>(xbuf, offs, dinv, meta, aggb, N);
  k_gemm<true ><<<GEMM_BLOCKS, 256, 0, stream>>>((const unsigned short*)aggb, wt,           b1, dinv, (unsigned short*)xbuf, N);
  k_spmm<<<spmm_grid, 256, 0, stream>>>(xbuf, offs, dinv, meta, aggb, N);
  k_gemm<true ><<<GEMM_BLOCKS, 256, 0, stream>>>((const unsigned short*)aggb, wt + 16384,   b2, dinv, (unsigned short*)xbuf, N);
  k_spmm<<<spmm_grid, 256, 0, stream>>>(xbuf, offs, dinv, meta, aggb, N);
  k_gemm<false><<<GEMM_BLOCKS, 256, 0, stream>>>((const unsigned short*)aggb, wt + 2*16384, b3, dinv, (unsigned short*)xbuf, N);

  k_pool <<<NGRAPH*POOL_S, 128, 0, stream>>>(xbuf, batch, part, N);
  k_final<<<NGRAPH, 128, 0, stream>>>(part, batch, Wl, bl, out, N);
}

// Round 10
// 443.371 us; speedup vs baseline: 1.3872x; 1.3872x over previous
//
#include <hip/hip_runtime.h>
#include <stdint.h>

#define C_HID 128
#define NGRAPH 64
#define COUT 64
#define POOL_S 64     // pool chunks per graph
#define NBLK 256      // edge-chunk blocks for cnt/scat
#define BKT 256       // nodes per bucket
#define NBUK_MAX 512
#define SCAN_CH 4096  // scan elements per block (256 thr x 16)

typedef short bf16x8 __attribute__((ext_vector_type(8)));
typedef float f32x4 __attribute__((ext_vector_type(4)));

__device__ __forceinline__ unsigned short f2bf(float f){
  unsigned int u = __builtin_bit_cast(unsigned int, f);
  u = u + 0x7FFFu + ((u >> 16) & 1u);   // RNE
  return (unsigned short)(u >> 16);
}
__device__ __forceinline__ float bflo(unsigned int u){
  return __builtin_bit_cast(float, u << 16);
}
__device__ __forceinline__ float bfhi(unsigned int u){
  return __builtin_bit_cast(float, u & 0xFFFF0000u);
}
__device__ __forceinline__ int clampi(int v, int lo, int hi){
  return v < lo ? lo : (v > hi ? hi : v);
}

__global__ void k_zero(float* __restrict__ out, int n){
  int i = blockIdx.x*blockDim.x + threadIdx.x;
  if (i < n) out[i] = 0.f;
}

// ---------- CSR build, pass 1: per-(block,bucket) histogram ----------
__global__ __launch_bounds__(256) void k_cnt(const int* __restrict__ dst,
                                             int* __restrict__ cntg,
                                             int E, int N, int NBUK, int chunk){
  __shared__ int cnt[NBUK_MAX];
  int blk = blockIdx.x, t = threadIdx.x;
  for (int b = t; b < NBUK; b += 256) cnt[b] = 0;
  __syncthreads();
  int e0 = blk*chunk, e1 = min(E, e0 + chunk);
  for (int e = e0 + t; e < e1; e += 256)
    atomicAdd(&cnt[clampi(dst[e], 0, N-1) >> 8], 1);
  __syncthreads();
  for (int b = t; b < NBUK; b += 256)
    cntg[b*NBLK + blk] = cnt[b];          // bucket-major layout for the scan
}

// ---------- pass 2: hierarchical exclusive scan of n counts ----------
__global__ __launch_bounds__(256) void k_scanA(const int* __restrict__ cnt,
                                               int* __restrict__ bsum, int n){
  __shared__ int red[256];
  int blk = blockIdx.x, t = threadIdx.x;
  int base = blk*SCAN_CH + t*16;
  int s = 0;
  #pragma unroll
  for (int j = 0; j < 16; ++j){ int i = base + j; s += (i < n) ? cnt[i] : 0; }
  red[t] = s; __syncthreads();
  for (int off = 128; off > 0; off >>= 1){
    if (t < off) red[t] += red[t + off];
    __syncthreads();
  }
  if (t == 0) bsum[blk] = red[0];
}

// single block; nb <= 256
__global__ __launch_bounds__(256) void k_scanB(const int* __restrict__ bsum,
                                               int* __restrict__ bbase,
                                               int* __restrict__ bases, int nb, int n){
  __shared__ int buf[256];
  int t = threadIdx.x;
  int v = (t < nb) ? bsum[t] : 0;
  buf[t] = v; __syncthreads();
  for (int off = 1; off < 256; off <<= 1){
    int add = (t >= off) ? buf[t-off] : 0;
    __syncthreads();
    buf[t] += add;
    __syncthreads();
  }
  if (t < nb) bbase[t] = buf[t] - v;       // exclusive
  if (t == nb-1) bases[n] = buf[t];        // total == E
}

__global__ __launch_bounds__(256) void k_scanC(const int* __restrict__ cnt,
                                               const int* __restrict__ bbase,
                                               int* __restrict__ bases, int n){
  __shared__ int buf[256];
  int blk = blockIdx.x, t = threadIdx.x;
  int base = blk*SCAN_CH + t*16;
  int loc[16]; int s = 0;
  #pragma unroll
  for (int j = 0; j < 16; ++j){ int i = base + j; loc[j] = (i < n) ? cnt[i] : 0; s += loc[j]; }
  buf[t] = s; __syncthreads();
  for (int off = 1; off < 256; off <<= 1){
    int add = (t >= off) ? buf[t-off] : 0;
    __syncthreads();
    buf[t] += add;
    __syncthreads();
  }
  int run = bbase[blk] + buf[t] - s;       // exclusive prefix for this thread
  #pragma unroll
  for (int j = 0; j < 16; ++j){
    int i = base + j;
    if (i < n) bases[i] = run;
    run += loc[j];
  }
}

// ---------- pass 3: scatter packed records into per-(block,bucket) segments ----------
// Each block writes only its own contiguous segments -> one XCD per line, no global atomics.
__global__ __launch_bounds__(256) void k_scat(const int* __restrict__ src,
                                              const int* __restrict__ dst,
                                              const int* __restrict__ bases,
                                              unsigned int* __restrict__ rec,
                                              int E, int N, int NBUK, int chunk){
  __shared__ int cur[NBUK_MAX];
  int blk = blockIdx.x, t = threadIdx.x;
  for (int b = t; b < NBUK; b += 256) cur[b] = bases[b*NBLK + blk];
  __syncthreads();
  int e0 = blk*chunk, e1 = min(E, e0 + chunk);
  for (int e = e0 + t; e < e1; e += 256){
    int d = clampi(dst[e], 0, N-1);
    int s = clampi(src[e], 0, N-1);
    int p = atomicAdd(&cur[d >> 8], 1);    // LDS atomic
    rec[p] = (unsigned int)s | ((unsigned int)(d & 255) << 24);
  }
}

// ---------- pass 4: per-bucket local CSR (offs, dinv, meta) ----------
__global__ __launch_bounds__(256) void k_csr(const unsigned int* __restrict__ rec,
                                             const int* __restrict__ bases,
                                             int* __restrict__ offs, float* __restrict__ dinv,
                                             int* __restrict__ meta, int E, int N, int NBUK){
  __shared__ int cnt[BKT], loff[BKT], cur[BKT];
  int b = blockIdx.x, t = threadIdx.x;
  cnt[t] = 0;
  __syncthreads();
  int r0 = bases[b*NBLK];
  int r1 = (b+1 < NBUK) ? bases[(b+1)*NBLK] : E;
  for (int i = r0 + t; i < r1; i += 256)
    atomicAdd(&cnt[rec[i] >> 24], 1);
  __syncthreads();
  loff[t] = cnt[t];
  __syncthreads();
  for (int off = 1; off < BKT; off <<= 1){
    int add = (t >= off) ? loff[t - off] : 0;
    __syncthreads();
    loff[t] += add;
    __syncthreads();
  }
  int excl = loff[t] - cnt[t];
  cur[t] = r0 + excl;
  int node = b*BKT + t;
  if (node < N){
    offs[node] = r0 + excl;
    dinv[node] = rsqrtf((float)(cnt[t] + 1));   // +1 = self loop
  }
  if (b == NBUK-1 && t == 0) offs[N] = E;
  __syncthreads();
  for (int i = r0 + t; i < r1; i += 256){
    unsigned int r = rec[i];
    int p = atomicAdd(&cur[r >> 24], 1);
    meta[p] = (int)(r & 0x00FFFFFFu);
  }
}

// ---------- y0 = dinv * x0, fp32 -> packed bf16; also zero row N (gather sink) ----------
__global__ void k_xcast(const float2* __restrict__ x, const float* __restrict__ dinv,
                        unsigned int* __restrict__ o, int N){
  int i = blockIdx.x*256 + threadIdx.x;
  int tot = N*64;
  if (i < tot){
    float2 v = x[i];
    float dn = dinv[i >> 6];
    o[i] = (unsigned int)f2bf(v.x*dn) | ((unsigned int)f2bf(v.y*dn) << 16);
  } else if (i < tot + 64){
    o[i] = 0;                       // zero row at index N
  }
}

// ---------- W fp32 [128][128] -> Wt bf16 [n][k] (3 weights) ----------
__global__ void k_prep(const float* __restrict__ W1, const float* __restrict__ W2,
                       const float* __restrict__ W3, unsigned short* __restrict__ Wt){
  int idx = blockIdx.x*256 + threadIdx.x;     // grid = 192 blocks
  int w = idx >> 14;                           // 16384 per weight
  int r = idx & 16383;
  int n = r & 127, k = r >> 7;
  const float* W = (w == 0) ? W1 : (w == 1) ? W2 : W3;
  Wt[(size_t)w*16384 + (size_t)n*128 + k] = f2bf(W[k*128 + n]);
}

// ---------- SpMM: agg[i] = dinv[i] * ( y[i] + sum_e y[src_e] ) ----------
// y pre-scaled by dinv. One wave per node (uniform): meta reads are s_loads,
// gathers are SGPR-base + lane-offset. Tail gathers hit zero row N.
__global__ void k_spmm(const unsigned int* __restrict__ y, const int* __restrict__ offs,
                       const float* __restrict__ dinv, const int* __restrict__ meta,
                       unsigned int* __restrict__ agg, int N){
  int wv   = __builtin_amdgcn_readfirstlane(threadIdx.x >> 6);
  int lane = threadIdx.x & 63;
  int node = blockIdx.x*4 + wv;
  if (node >= N) return;
  int e0 = offs[node], e1 = offs[node+1];
  int cnt = e1 - e0;
  const int* mrow = meta + e0;

  float ax, ay;
  { unsigned int u = y[(size_t)node*64 + lane];   // self loop (y already dinv-scaled)
    ax = bflo(u); ay = bfhi(u); }

  for (int e = 0; e < cnt; e += 8){
    int s[8]; unsigned int u[8];
    #pragma unroll
    for (int j = 0; j < 8; ++j){
      int ij = e + j;
      int sj = mrow[ij];                           // uniform -> s_load (junk ok past cnt)
      s[j] = (ij < cnt) ? sj : N;                  // tail -> zero row
    }
    #pragma unroll
    for (int j = 0; j < 8; ++j)
      u[j] = y[(size_t)s[j]*64 + lane];            // SGPR base + lane offset
    #pragma unroll
    for (int j = 0; j < 8; ++j){
      ax += bflo(u[j]);
      ay += bfhi(u[j]);
    }
  }
  float dn = dinv[node];
  ax *= dn; ay *= dn;
  agg[(size_t)node*64 + lane] = (unsigned int)f2bf(ax) | ((unsigned int)f2bf(ay) << 16);
}

// ---------- GEMM: out = relu(A[Mx128] @ W + b) [* dinv[row] if SC] ----------
#define GEMM_BLOCKS 512
template<bool SC>
__global__ __launch_bounds__(256) void k_gemm(const unsigned short* __restrict__ A,
                                              const unsigned short* __restrict__ Wt,
                                              const float* __restrict__ bias,
                                              const float* __restrict__ scale,
                                              unsigned short* __restrict__ out, int M){
  __shared__ unsigned short wt[128*136];
  {
    const uint4* wsrc = (const uint4*)Wt;     // 4096 uint4 (8 shorts each)
    for (int i = threadIdx.x; i < 4096; i += 256){
      uint4 v = wsrc[i];
      int n = i >> 4, kblk = i & 15;          // row = 16 uint4
      *(uint4*)&wt[n*136 + kblk*8] = v;
    }
  }
  __syncthreads();

  int wv = threadIdx.x >> 6, lane = threadIdx.x & 63;
  int q = lane >> 4, ln = lane & 15;
  int tiles = (M + 63) >> 6;

  for (int tile = blockIdx.x; tile < tiles; tile += GEMM_BLOCKS){
    int m0 = tile*64 + wv*16;
    int arow = m0 + ln;
    bool arow_ok = (arow < M);
    int arow_s = arow_ok ? arow : 0;

    f32x4 zero = {0.f, 0.f, 0.f, 0.f};
    f32x4 acc[8];
    #pragma unroll
    for (int t = 0; t < 8; ++t) acc[t] = zero;

    #pragma unroll
    for (int kk = 0; kk < 4; ++kk){
      bf16x8 a;
      if (arow_ok){
        __builtin_memcpy(&a, A + (size_t)arow_s*128 + kk*32 + q*8, 16);
      } else {
        a = (bf16x8){0,0,0,0,0,0,0,0};
      }
      #pragma unroll
      for (int t = 0; t < 8; ++t){
        bf16x8 b;
        __builtin_memcpy(&b, &wt[(t*16 + ln)*136 + kk*32 + q*8], 16);
        acc[t] = __builtin_amdgcn_mfma_f32_16x16x32_bf16(a, b, acc[t], 0, 0, 0);
      }
    }
    float sc[4];
    #pragma unroll
    for (int r = 0; r < 4; ++r){
      int row = m0 + q*4 + r;
      sc[r] = (SC && row < M) ? scale[row] : 1.0f;
    }
    #pragma unroll
    for (int t = 0; t < 8; ++t){
      float bv = bias[t*16 + ln];
      #pragma unroll
      for (int r = 0; r < 4; ++r){
        int row = m0 + q*4 + r;
        if (row < M){
          float v = acc[t][r] + bv;
          v = v > 0.f ? v : 0.f;
          if (SC) v *= sc[r];
          out[(size_t)row*128 + t*16 + ln] = f2bf(v);
        }
      }
    }
  }
}

// ---------- pooling ----------
__device__ __forceinline__ int lower_bound_i(const int* arr, int n, int val){
  int lo = 0, hi = n;
  while (lo < hi){ int mid = (lo + hi) >> 1; if (arr[mid] < val) lo = mid + 1; else hi = mid; }
  return lo;
}

__global__ void k_pool(const unsigned int* __restrict__ x, const int* __restrict__ batch,
                       float* __restrict__ partial, int N){
  int g = blockIdx.x / POOL_S, s = blockIdx.x % POOL_S;
  int h = threadIdx.x >> 6;
  int lane = threadIdx.x & 63;
  int rs = clampi(lower_bound_i(batch, N, g), 0, N);
  int re = clampi(lower_bound_i(batch, N, g + 1), rs, N);
  int len = re - rs;
  int a = rs + (int)(((long long)len * s) / POOL_S);
  int b = rs + (int)(((long long)len * (s + 1)) / POOL_S);
  float ax = 0.f, ay = 0.f;
  for (int i = a + h; i < b; i += 2){
    unsigned int u = x[(size_t)i*64 + lane];
    ax += bflo(u);
    ay += bfhi(u);
  }
  float* p = partial + ((size_t)(g*POOL_S + s)*2 + h)*C_HID;
  p[2*lane]   = ax;
  p[2*lane+1] = ay;
}

__global__ void k_final(const float* __restrict__ partial, const int* __restrict__ batch,
                        const float* __restrict__ Wl, const float* __restrict__ bl,
                        float* __restrict__ out, int N){
  __shared__ float sums[C_HID];
  int g = blockIdx.x;
  int t = threadIdx.x;
  float acc = 0.f;
  const float* p = partial + (size_t)g*POOL_S*2*C_HID;
  for (int j = 0; j < POOL_S*2; ++j)
    acc += p[j*C_HID + t];
  sums[t] = acc;
  __syncthreads();
  if (t < COUT){
    int rs = clampi(lower_bound_i(batch, N, g), 0, N);
    int re = clampi(lower_bound_i(batch, N, g + 1), rs, N);
    float inv = 1.0f / fmaxf((float)(re - rs), 1.0f);
    float o = 0.f;
    for (int k = 0; k < 128; ++k)
      o += sums[k] * Wl[k*COUT + t];
    out[g*COUT + t] = o * inv + bl[t];
  }
}

extern "C" void kernel_launch(void* const* d_in, const int* in_sizes, int n_in,
                              void* d_out, int out_size, void* d_ws, size_t ws_size,
                              hipStream_t stream){
  const float* x0 = (const float*)d_in[0];
  const int* ei   = (const int*)d_in[1];
  const int* batch= (const int*)d_in[2];
  const float* W1 = (const float*)d_in[3];
  const float* b1 = (const float*)d_in[4];
  const float* W2 = (const float*)d_in[5];
  const float* b2 = (const float*)d_in[6];
  const float* W3 = (const float*)d_in[7];
  const float* b3 = (const float*)d_in[8];
  const float* Wl = (const float*)d_in[9];
  const float* bl = (const float*)d_in[10];
  float* out = (float*)d_out;

  int E = in_sizes[1] / 2;
  int N = in_sizes[2];
  const int* src = ei;
  const int* dst = ei + E;
  int NBUK = (N + BKT - 1) / BKT;
  int chunk = (E + NBLK - 1) / NBLK;
  int ncnt = NBUK * NBLK;
  int nsb  = (ncnt + SCAN_CH - 1) / SCAN_CH;   // scan blocks

  size_t off_acc = 0;
  auto carve = [&](size_t bytes)->size_t{
    size_t r = off_acc; off_acc += (bytes + 255) & ~(size_t)255; return r;
  };
  size_t part_bytes = (size_t)NGRAPH*POOL_S*2*C_HID*4;      // 4 MB
  size_t rec_bytes  = (size_t)E*4;                          // 6.4 MB
  size_t o_cnt   = carve((size_t)ncnt*4);                   // per-(bucket,block) counts
  size_t o_bases = carve((size_t)(ncnt+1)*4);
  size_t o_bsum  = carve(256*4);
  size_t o_bbase = carve(256*4);
  size_t o_offs  = carve((size_t)(N+1)*4);
  size_t o_dinv  = carve((size_t)N*4);
  size_t o_meta  = carve((size_t)E*4);                      // compact CSR src list
  size_t o_u     = carve(rec_bytes > part_bytes ? rec_bytes : part_bytes); // rec/part union
  size_t o_aggb  = carve((size_t)N*C_HID*2);                // bf16 ping
  size_t o_xbuf  = carve((size_t)(N+1)*C_HID*2);            // bf16 pong (+ zero row N)
  size_t o_wt    = carve((size_t)3*128*128*2);              // bf16 Wt x3
  size_t need = off_acc;

  if (ws_size < need || NBUK > NBUK_MAX || nsb > 256){
    k_zero<<<(out_size+255)/256, 256, 0, stream>>>(out, out_size);
    return;
  }

  char* base = (char*)d_ws;
  int* cntg  = (int*)(base + o_cnt);
  int* bases = (int*)(base + o_bases);
  int* bsum  = (int*)(base + o_bsum);
  int* bbase = (int*)(base + o_bbase);
  int* offs  = (int*)(base + o_offs);
  float* dinv= (float*)(base + o_dinv);
  int* meta  = (int*)(base + o_meta);
  unsigned int* rec  = (unsigned int*)(base + o_u);
  float* part        = (float*)(base + o_u);                // aliased (disjoint lifetime)
  unsigned int* aggb = (unsigned int*)(base + o_aggb);
  unsigned int* xbuf = (unsigned int*)(base + o_xbuf);
  unsigned short* wt = (unsigned short*)(base + o_wt);

  k_cnt  <<<NBLK, 256, 0, stream>>>(dst, cntg, E, N, NBUK, chunk);
  k_scanA<<<nsb, 256, 0, stream>>>(cntg, bsum, ncnt);
  k_scanB<<<1, 256, 0, stream>>>(bsum, bbase, bases, nsb, ncnt);
  k_scanC<<<nsb, 256, 0, stream>>>(cntg, bbase, bases, ncnt);
  k_scat <<<NBLK, 256, 0, stream>>>(src, dst, bases, rec, E, N, NBUK, chunk);
  k_csr  <<<NBUK, BKT, 0, stream>>>(rec, bases, offs, dinv, meta, E, N, NBUK);

  k_xcast<<<(N*64 + 64 + 255)/256, 256, 0, stream>>>((const float2*)x0, dinv, xbuf, N);
  k_prep <<<192, 256, 0, stream>>>(W1, W2, W3, wt);

  int spmm_grid = (N + 3) / 4;     // 4 waves/block, one wave per node

  k_spmm<<<spmm_grid, 256, 0, stream>>>(xbuf, offs, dinv, meta, aggb, N);
  k_gemm<true ><<<GEMM_BLOCKS, 256, 0, stream>>>((const unsigned short*)aggb, wt,           b1, dinv, (unsigned short*)xbuf, N);
  k_spmm<<<spmm_grid, 256, 0, stream>>>(xbuf, offs, dinv, meta, aggb, N);
  k_gemm<true ><<<GEMM_BLOCKS, 256, 0, stream>>>((const unsigned short*)aggb, wt + 16384,   b2, dinv, (unsigned short*)xbuf, N);
  k_spmm<<<spmm_grid, 256, 0, stream>>>(xbuf, offs, dinv, meta, aggb, N);
  k_gemm<false><<<GEMM_BLOCKS, 256, 0, stream>>>((const unsigned short*)aggb, wt + 2*16384, b3, dinv, (unsigned short*)xbuf, N);

  k_pool <<<NGRAPH*POOL_S, 128, 0, stream>>>(xbuf, batch, part, N);
  k_final<<<NGRAPH, 128, 0, stream>>>(part, batch, Wl, bl, out, N);
}